// Round 7
// baseline (63.528 us; speedup 1.0000x reference)
//
#include <hip/hip_runtime.h>

// Shallow water RHS, N=4096, periodic BC, 2nd-order central differences.
// dh = -d1x((1+h)u) - d1y((1+h)v)
// du = MU*(d2x(u)+d2y(u)) - G*d1x(h)
// dv = MU*(d2x(v)+d2y(v)) - G*d1y(h)
//
// Round 7: round-5 structure (RPT=8, XCD band swizzle, all-upfront loads,
// passing @62.4us) + output stores via raw_buffer_store with explicit
// cache policy aux = NT|SC1 (no-allocate / streaming past L2 and MALL).
// Compiler-lowered (no hand-written asm operands — round 6's inline asm
// corrupted the data operand). Goal: stop the 201 MB/replay write stream
// from evicting the L3-resident input -> FETCH ~100MB -> ~0.

typedef float f4  __attribute__((ext_vector_type(4)));
typedef int   v4i __attribute__((ext_vector_type(4)));

constexpr int    NN      = 4096;
constexpr long   PLANE   = (long)NN * NN;
constexpr float  INV2DX  = 2048.0f;              // 1/(2*DX), DX = 1/N
constexpr float  MU_LAP  = 1e-4f * 16777216.0f;  // MU / DX^2
constexpr float  G2DX    = 9.8f * 2048.0f;       // G / (2*DX)
constexpr int    RPT     = 8;                    // rows per thread
constexpr int    BX      = NN / (4 * 256);       // 4  x-blocks
constexpr int    BY      = NN / RPT;             // 512 y-blocks
constexpr int    NWG     = BX * BY;              // 2048 (divisible by 8 XCDs)

// CPOL bits, gfx940+/gfx950: SC0=1, NT=2, SC1=16.  NT|SC1 = 18.
constexpr int STREAM_CPOL = 18;

__device__ __forceinline__ void store_stream(float* base, long elem_off, f4 val,
                                             v4i rsrc) {
#if __has_builtin(__builtin_amdgcn_raw_buffer_store_v4f32)
    __builtin_amdgcn_raw_buffer_store_v4f32(val, rsrc, (int)(elem_off * 4), 0,
                                            STREAM_CPOL);
#else
    __builtin_nontemporal_store(val, (f4*)(base + elem_off));
#endif
}

__global__ __launch_bounds__(256) void swm_rhs(const float* __restrict__ st,
                                               float* __restrict__ out) {
    // XCD band swizzle: hardware round-robins flat blockIdx across 8 XCDs;
    // remap so XCD k owns the contiguous y-band [k*BY/8, (k+1)*BY/8).
    const int flat = blockIdx.x;
    const int swz  = (flat & 7) * (NWG / 8) + (flat >> 3);
    const int bx   = swz & (BX - 1);
    const int by   = swz / BX;

    const int tid  = threadIdx.x;
    const int lane = tid & 63;
    const int j    = (bx * 256 + tid) * 4;
    const int i0   = by * RPT;

    const float* __restrict__ h = st;
    const float* __restrict__ u = st + PLANE;
    const float* __restrict__ v = st + 2 * PLANE;

    // SRSRC over the whole output buffer (3 planes = 201326592 bytes < 2^31):
    // stride=0 -> num_records is byte size; word3 = raw untyped dword access.
    const unsigned long long ob = (unsigned long long)(const void*)out;
    v4i rsrc;
    rsrc[0] = (int)(ob & 0xffffffffull);
    rsrc[1] = (int)(ob >> 32);           // stride = 0
    rsrc[2] = (int)(3l * PLANE * 4);     // num_records (bytes)
    rsrc[3] = 0x00020000;

    // --- all row loads up front: rows i0-1 .. i0+RPT, 3 planes, dwordx4 each
    f4 H[RPT + 2], U[RPT + 2], V[RPT + 2];
#pragma unroll
    for (int r = 0; r < RPT + 2; ++r) {
        int row = i0 + r - 1;
        row = (row < 0) ? NN - 1 : (row >= NN ? row - NN : row);
        const long off = (long)row * NN + j;
        H[r] = *(const f4*)(h + off);
        U[r] = *(const f4*)(u + off);
        V[r] = *(const f4*)(v + off);
    }

    // --- edge (wrap-column) loads: lane 0 needs left col, lane 63 right col.
    const int jl = (j == 0) ? NN - 1 : j - 1;
    const int jr = (j + 4 == NN) ? 0 : j + 4;
    const long ecol = (lane == 0) ? jl : jr;
    float eh[RPT] = {}, eu[RPT] = {}, ev[RPT] = {};
    if (lane == 0 || lane == 63) {
#pragma unroll
        for (int r = 0; r < RPT; ++r) {
            const long off = (long)(i0 + r) * NN + ecol;
            eh[r] = h[off]; eu[r] = u[off]; ev[r] = v[off];
        }
    }

#pragma unroll
    for (int r = 0; r < RPT; ++r) {
        const f4 hP = H[r], hC = H[r + 1], hS = H[r + 2];
        const f4 uP = U[r], uC = U[r + 1], uS = U[r + 2];
        const f4 vP = V[r], vC = V[r + 1], vS = V[r + 2];
        const long rc = (long)(i0 + r) * NN + j;

        float hL = __shfl_up(hC[3], 1);
        float uL = __shfl_up(uC[3], 1);
        float vL = __shfl_up(vC[3], 1);
        float hR = __shfl_down(hC[0], 1);
        float uR = __shfl_down(uC[0], 1);
        float vR = __shfl_down(vC[0], 1);
        if (lane == 0)  { hL = eh[r]; uL = eu[r]; vL = ev[r]; }
        if (lane == 63) { hR = eh[r]; uR = eu[r]; vR = ev[r]; }

        const float hx[6] = {hL, hC[0], hC[1], hC[2], hC[3], hR};
        const float ux[6] = {uL, uC[0], uC[1], uC[2], uC[3], uR};
        const float vx[6] = {vL, vC[0], vC[1], vC[2], vC[3], vR};

        f4 rh, ru, rv;
#pragma unroll
        for (int k = 0; k < 4; ++k) {
            const float hl = hx[k], hr = hx[k + 2];
            const float ul = ux[k], uc = ux[k + 1], ur = ux[k + 2];
            const float vl = vx[k], vc = vx[k + 1], vr = vx[k + 2];

            rh[k] = -INV2DX * (((1.0f + hr) * ur - (1.0f + hl) * ul)
                             + ((1.0f + hS[k]) * vS[k] - (1.0f + hP[k]) * vP[k]));
            ru[k] = MU_LAP * (ul + ur + uP[k] + uS[k] - 4.0f * uc) - G2DX * (hr - hl);
            rv[k] = MU_LAP * (vl + vr + vP[k] + vS[k] - 4.0f * vc) - G2DX * (hS[k] - hP[k]);
        }

        store_stream(out, rc,             rh, rsrc);
        store_stream(out, PLANE + rc,     ru, rsrc);
        store_stream(out, 2 * PLANE + rc, rv, rsrc);
    }
}

extern "C" void kernel_launch(void* const* d_in, const int* in_sizes, int n_in,
                              void* d_out, int out_size, void* d_ws, size_t ws_size,
                              hipStream_t stream) {
    // d_in[0] = t (scalar, unused by RHS), d_in[1] = state [3,N,N] fp32
    const float* state = (const float*)d_in[1];
    float* out = (float*)d_out;
    swm_rhs<<<dim3(NWG), dim3(256), 0, stream>>>(state, out);
}

// Round 8
// 61.646 us; speedup vs baseline: 1.0305x; 1.0305x over previous
//
#include <hip/hip_runtime.h>

// Shallow water RHS, N=4096, periodic BC, 2nd-order central differences.
// dh = -d1x((1+h)u) - d1y((1+h)v)
// du = MU*(d2x(u)+d2y(u)) - G*d1x(h)
// dv = MU*(d2x(v)+d2y(v)) - G*d1y(h)
//
// FINAL (revert to round-5 best, 62.4 us): RPT=8 rows/thread, XCD band
// swizzle, all-upfront loads (30 dwordx4 in flight before first wait),
// hoisted wrap-column edge loads, nontemporal dwordx4 stores.
//
// Roofline note: compulsory fabric traffic = 201 MB read + 201 MB write;
// at the demonstrated 6.9 TB/s device ceiling that is 58.3 us; this kernel
// runs ~62 us (>93%). The residual ~100 MB/replay HBM re-fetch is MALL
// thrash (input+output = 402 MB > 256 MiB Infinity Cache) and is not
// controllable via store cache-policy bits (round-7 null result).

typedef float f4 __attribute__((ext_vector_type(4)));

constexpr int    NN      = 4096;
constexpr long   PLANE   = (long)NN * NN;
constexpr float  INV2DX  = 2048.0f;              // 1/(2*DX), DX = 1/N
constexpr float  MU_LAP  = 1e-4f * 16777216.0f;  // MU / DX^2
constexpr float  G2DX    = 9.8f * 2048.0f;       // G / (2*DX)
constexpr int    RPT     = 8;                    // rows per thread
constexpr int    BX      = NN / (4 * 256);       // 4  x-blocks
constexpr int    BY      = NN / RPT;             // 512 y-blocks
constexpr int    NWG     = BX * BY;              // 2048 (divisible by 8 XCDs)

__global__ __launch_bounds__(256) void swm_rhs(const float* __restrict__ st,
                                               float* __restrict__ out) {
    // XCD band swizzle: hardware round-robins flat blockIdx across 8 XCDs;
    // remap so XCD k owns the contiguous y-band [k*BY/8, (k+1)*BY/8).
    const int flat = blockIdx.x;
    const int swz  = (flat & 7) * (NWG / 8) + (flat >> 3);
    const int bx   = swz & (BX - 1);
    const int by   = swz / BX;

    const int tid  = threadIdx.x;
    const int lane = tid & 63;
    const int j    = (bx * 256 + tid) * 4;
    const int i0   = by * RPT;

    const float* __restrict__ h = st;
    const float* __restrict__ u = st + PLANE;
    const float* __restrict__ v = st + 2 * PLANE;

    // --- all row loads up front: rows i0-1 .. i0+RPT, 3 planes, dwordx4 each
    f4 H[RPT + 2], U[RPT + 2], V[RPT + 2];
#pragma unroll
    for (int r = 0; r < RPT + 2; ++r) {
        int row = i0 + r - 1;
        row = (row < 0) ? NN - 1 : (row >= NN ? row - NN : row);
        const long off = (long)row * NN + j;
        H[r] = *(const f4*)(h + off);
        U[r] = *(const f4*)(u + off);
        V[r] = *(const f4*)(v + off);
    }

    // --- edge (wrap-column) loads: lane 0 needs left col, lane 63 right col.
    const int jl = (j == 0) ? NN - 1 : j - 1;
    const int jr = (j + 4 == NN) ? 0 : j + 4;
    const long ecol = (lane == 0) ? jl : jr;
    float eh[RPT] = {}, eu[RPT] = {}, ev[RPT] = {};
    if (lane == 0 || lane == 63) {
#pragma unroll
        for (int r = 0; r < RPT; ++r) {
            const long off = (long)(i0 + r) * NN + ecol;
            eh[r] = h[off]; eu[r] = u[off]; ev[r] = v[off];
        }
    }

#pragma unroll
    for (int r = 0; r < RPT; ++r) {
        const f4 hP = H[r], hC = H[r + 1], hS = H[r + 2];
        const f4 uP = U[r], uC = U[r + 1], uS = U[r + 2];
        const f4 vP = V[r], vC = V[r + 1], vS = V[r + 2];
        const long rc = (long)(i0 + r) * NN + j;

        float hL = __shfl_up(hC[3], 1);
        float uL = __shfl_up(uC[3], 1);
        float vL = __shfl_up(vC[3], 1);
        float hR = __shfl_down(hC[0], 1);
        float uR = __shfl_down(uC[0], 1);
        float vR = __shfl_down(vC[0], 1);
        if (lane == 0)  { hL = eh[r]; uL = eu[r]; vL = ev[r]; }
        if (lane == 63) { hR = eh[r]; uR = eu[r]; vR = ev[r]; }

        const float hx[6] = {hL, hC[0], hC[1], hC[2], hC[3], hR};
        const float ux[6] = {uL, uC[0], uC[1], uC[2], uC[3], uR};
        const float vx[6] = {vL, vC[0], vC[1], vC[2], vC[3], vR};

        f4 rh, ru, rv;
#pragma unroll
        for (int k = 0; k < 4; ++k) {
            const float hl = hx[k], hr = hx[k + 2];
            const float ul = ux[k], uc = ux[k + 1], ur = ux[k + 2];
            const float vl = vx[k], vc = vx[k + 1], vr = vx[k + 2];

            rh[k] = -INV2DX * (((1.0f + hr) * ur - (1.0f + hl) * ul)
                             + ((1.0f + hS[k]) * vS[k] - (1.0f + hP[k]) * vP[k]));
            ru[k] = MU_LAP * (ul + ur + uP[k] + uS[k] - 4.0f * uc) - G2DX * (hr - hl);
            rv[k] = MU_LAP * (vl + vr + vP[k] + vS[k] - 4.0f * vc) - G2DX * (hS[k] - hP[k]);
        }

        // outputs are write-once: nontemporal, keep L2/L3 for reused inputs
        __builtin_nontemporal_store(rh, (f4*)(out + rc));
        __builtin_nontemporal_store(ru, (f4*)(out + PLANE + rc));
        __builtin_nontemporal_store(rv, (f4*)(out + 2 * PLANE + rc));
    }
}

extern "C" void kernel_launch(void* const* d_in, const int* in_sizes, int n_in,
                              void* d_out, int out_size, void* d_ws, size_t ws_size,
                              hipStream_t stream) {
    // d_in[0] = t (scalar, unused by RHS), d_in[1] = state [3,N,N] fp32
    const float* state = (const float*)d_in[1];
    float* out = (float*)d_out;
    swm_rhs<<<dim3(NWG), dim3(256), 0, stream>>>(state, out);
}